// Round 7
// baseline (1273.959 us; speedup 1.0000x reference)
//
#include <hip/hip_runtime.h>
#include <hip/hip_bf16.h>

#define S_LEN 2048
#define HID_DIM 4096
#define NH 32
#define HD 128
#define NQKV 12288

typedef _Float16 half2v __attribute__((ext_vector_type(2)));
typedef _Float16 half4v __attribute__((ext_vector_type(4)));
typedef _Float16 half8v __attribute__((ext_vector_type(8)));
typedef float f32x4 __attribute__((ext_vector_type(4)));

typedef const __attribute__((address_space(1))) unsigned int* gas_u32;
typedef __attribute__((address_space(3))) unsigned int* las_u32;

__device__ inline void g2lds16(const _Float16* g, _Float16* l) {
  __builtin_amdgcn_global_load_lds((gas_u32)g, (las_u32)l, 16, 0, 0);
}

__device__ inline void store_out(_Float16* p, float v) { *p = (_Float16)v; }
__device__ inline void store_out(float* p, float v) { *p = v; }

// ---------------- dequant W[K,N] int32 -> Wt[N,K] f16 (transposed) ----------------
__global__ __launch_bounds__(256) void dequant_w(const int* __restrict__ W,
                                                 const float* __restrict__ scal,
                                                 const float* __restrict__ zer,
                                                 _Float16* __restrict__ Wt, int K, int N) {
  __shared__ _Float16 lT[64 * 84];  // [n][k]
  const int k0 = blockIdx.y * 64, n0 = blockIdx.x * 64;
  const int tid = threadIdx.x, c = tid & 63, rp = tid >> 6;
  const int g = k0 >> 7;  // 64 | 128 -> group uniform over tile
  const float sc = scal[(size_t)g * N + n0 + c];
  const float zp = zer[(size_t)g * N + n0 + c];
#pragma unroll
  for (int i = 0; i < 8; ++i) {
    const int k = i * 8 + rp * 2;
    const float q0 = (float)W[(size_t)(k0 + k) * N + n0 + c];
    const float q1 = (float)W[(size_t)(k0 + k + 1) * N + n0 + c];
    half2v p;
    p[0] = (_Float16)((q0 - zp) * sc);
    p[1] = (_Float16)((q1 - zp) * sc);
    *(half2v*)&lT[c * 84 + k] = p;
  }
  __syncthreads();
  const int kc = tid & 7, nr0 = tid >> 3;
#pragma unroll
  for (int i = 0; i < 2; ++i) {
    const int n = nr0 + 32 * i;
    union { half8v v8; half4v v4[2]; } u;
    u.v4[0] = *(const half4v*)&lT[n * 84 + kc * 8];
    u.v4[1] = *(const half4v*)&lT[n * 84 + kc * 8 + 4];
    *(half8v*)&Wt[(size_t)(n0 + n) * K + k0 + kc * 8] = u.v8;
  }
}

// ---------------- hidden f32 -> f16 ----------------
__global__ __launch_bounds__(256) void conv_a(const float* __restrict__ A, _Float16* __restrict__ Af) {
  const int i = blockIdx.x * 256 + threadIdx.x;
  const float4 t = ((const float4*)A)[i];
  half4v r;
  r[0] = (_Float16)t.x; r[1] = (_Float16)t.y; r[2] = (_Float16)t.z; r[3] = (_Float16)t.w;
  ((half4v*)Af)[i] = r;
}

// ---------------- m97-structure f16 GEMM + XOR-swizzled LDS ----------------
template <typename CT>
__global__ __launch_bounds__(256) void gemm_f16(const _Float16* __restrict__ A,
                                                const _Float16* __restrict__ Bt,
                                                CT* __restrict__ C, int M, int N, int K) {
  __shared__ _Float16 lA[128 * 32];
  __shared__ _Float16 lB[128 * 32];

  const int tid = threadIdx.x;
  const int wave = tid >> 6, lane = tid & 63;
  const int quad = lane >> 4, l16 = lane & 15;
  const int wr = wave >> 1, wc = wave & 1;
  const int mb = blockIdx.y, nb = blockIdx.x;

  f32x4 acc[4][4];
  const f32x4 zero4 = {0.f, 0.f, 0.f, 0.f};
#pragma unroll
  for (int mt = 0; mt < 4; ++mt)
#pragma unroll
    for (int nt = 0; nt < 4; ++nt) acc[mt][nt] = zero4;

  const _Float16* Ab = A + (size_t)(mb * 128) * K;
  const _Float16* Bb = Bt + (size_t)(nb * 128) * K;
  const int lrow = lane >> 2;
  const int lkc = ((lane & 3) ^ ((lane >> 3) & 3)) * 8;
  const int sq = (quad ^ ((l16 >> 1) & 3)) * 8;

  for (int k0 = 0; k0 < K; k0 += 32) {
#pragma unroll
    for (int p = 0; p < 2; ++p) {
      const int issue = wave * 2 + p;
      const int row = issue * 16 + lrow;
      g2lds16(Ab + (size_t)row * K + k0 + lkc, &lA[issue * 512]);
      g2lds16(Bb + (size_t)row * K + k0 + lkc, &lB[issue * 512]);
    }
    __syncthreads();

    half8v af[4], bf[4];
#pragma unroll
    for (int mt = 0; mt < 4; ++mt) af[mt] = *(half8v*)&lA[(wr * 64 + mt * 16 + l16) * 32 + sq];
#pragma unroll
    for (int nt = 0; nt < 4; ++nt) bf[nt] = *(half8v*)&lB[(wc * 64 + nt * 16 + l16) * 32 + sq];
#pragma unroll
    for (int mt = 0; mt < 4; ++mt)
#pragma unroll
      for (int nt = 0; nt < 4; ++nt)
        acc[mt][nt] = __builtin_amdgcn_mfma_f32_16x16x32_f16(af[mt], bf[nt], acc[mt][nt], 0, 0, 0);
    __syncthreads();
  }

#pragma unroll
  for (int mt = 0; mt < 4; ++mt) {
#pragma unroll
    for (int nt = 0; nt < 4; ++nt) {
#pragma unroll
      for (int i = 0; i < 4; ++i) {
        const int row = mb * 128 + wr * 64 + mt * 16 + quad * 4 + i;
        const int col = nb * 128 + wc * 64 + nt * 16 + l16;
        store_out(C + (size_t)row * N + col, acc[mt][nt][i]);
      }
    }
  }
}

// ---------------- RoPE on Q,K -> [h][s][d]; V -> Vt [h][d][s] ----------------
__global__ __launch_bounds__(256) void rope_kernel(const _Float16* __restrict__ proj,
                                                   const int* __restrict__ pos,
                                                   _Float16* __restrict__ Q, _Float16* __restrict__ K,
                                                   _Float16* __restrict__ Vt) {
  const int h = blockIdx.x, sb = blockIdx.y;
  const int tid = threadIdx.x;
  const int s0 = sb * 64;

#pragma unroll
  for (int it = 0; it < 16; ++it) {
    const int idx = it * 256 + tid;
    const int sl = idx >> 6, j = idx & 63;
    const int s = s0 + sl;
    const float p = (float)pos[s];
    const float invrev = exp2f(-0.20762050593045455f * (float)j) * 0.15915494309189535f;
    const float rev = p * invrev;
    const float frac = rev - floorf(rev);
    const float sn = __builtin_amdgcn_sinf(frac);
    const float cs = __builtin_amdgcn_cosf(frac);
    const _Float16* rp = proj + (size_t)s * NQKV + h * HD;
    {
      const float x1 = (float)rp[j], x2 = (float)rp[j + 64];
      _Float16* qp = Q + ((size_t)h * S_LEN + s) * HD;
      qp[j] = (_Float16)(x1 * cs - x2 * sn);
      qp[j + 64] = (_Float16)(x2 * cs + x1 * sn);
    }
    {
      const float x1 = (float)rp[HID_DIM + j], x2 = (float)rp[HID_DIM + j + 64];
      _Float16* kp = K + ((size_t)h * S_LEN + s) * HD;
      kp[j] = (_Float16)(x1 * cs - x2 * sn);
      kp[j + 64] = (_Float16)(x2 * cs + x1 * sn);
    }
  }

  __shared__ _Float16 lV[64 * 132];
#pragma unroll
  for (int r = 0; r < 4; ++r) {
    const int cid = r * 256 + tid;
    const int sl = cid >> 4;
    const int d0 = (cid & 15) * 8;
    const _Float16* vp = proj + (size_t)(s0 + sl) * NQKV + 2 * HID_DIM + h * HD + d0;
    *(half4v*)&lV[sl * 132 + d0] = *(const half4v*)vp;
    *(half4v*)&lV[sl * 132 + d0 + 4] = *(const half4v*)(vp + 4);
  }
  __syncthreads();
#pragma unroll
  for (int it = 0; it < 32; ++it) {
    const int d = it * 4 + (tid >> 6);
    const int sl = tid & 63;
    Vt[((size_t)h * HD + d) * S_LEN + s0 + sl] = lV[sl * 132 + d];
  }
}

// ---------------- flash attention: wave = 16 q rows, grid (32,32) -> 4 waves/SIMD ----------------
// barrier-free (per-wave LDS), no running max (scores O(1)), V loads hoisted to tile top
__global__ __launch_bounds__(256) void flash_attn(const _Float16* __restrict__ Q,
                                                  const _Float16* __restrict__ Km,
                                                  const _Float16* __restrict__ Vt,
                                                  _Float16* __restrict__ O) {
  __shared__ _Float16 lP[4][16 * 40];  // per-wave P staging
  const int h = blockIdx.y;
  const int xb = blockIdx.x;
  const int qb = (xb & 1) ? (31 - (xb >> 1)) : (xb >> 1);  // light/heavy pairing over 32 blocks
  const int tid = threadIdx.x;
  const int wave = tid >> 6, lane = tid & 63;
  const int quad = lane >> 4, l16 = lane & 15;
  const int q0w = qb * 64 + wave * 16;
  const float scale = 0.08838834764831845f;

  const _Float16* Qh = Q + (size_t)h * S_LEN * HD;
  const _Float16* Kh = Km + (size_t)h * S_LEN * HD;
  const _Float16* Vh = Vt + (size_t)h * HD * S_LEN;

  half8v qf[4];
#pragma unroll
  for (int c = 0; c < 4; ++c)
    qf[c] = *(const half8v*)&Qh[(size_t)(q0w + l16) * HD + c * 32 + quad * 8];

  const f32x4 zero4 = {0.f, 0.f, 0.f, 0.f};
  f32x4 o[8];
  f32x4 lp = zero4;
#pragma unroll
  for (int c = 0; c < 8; ++c) o[c] = zero4;

  const int ntiles = (q0w >> 5) + 1;
  for (int kt = 0; kt < ntiles; ++kt) {
    // V loads first (consumed last -> hidden behind QK+exp chain)
    half8v vf[8];
#pragma unroll
    for (int c = 0; c < 8; ++c)
      vf[c] = *(const half8v*)&Vh[(size_t)(c * 16 + l16) * S_LEN + kt * 32 + quad * 8];

    half8v kf[2][4];
#pragma unroll
    for (int hf = 0; hf < 2; ++hf)
#pragma unroll
      for (int c = 0; c < 4; ++c)
        kf[hf][c] = *(const half8v*)&Kh[(size_t)(kt * 32 + hf * 16 + l16) * HD + c * 32 + quad * 8];

    f32x4 s[2];
#pragma unroll
    for (int hf = 0; hf < 2; ++hf) {
      s[hf] = zero4;
#pragma unroll
      for (int c = 0; c < 4; ++c)
        s[hf] = __builtin_amdgcn_mfma_f32_16x16x32_f16(qf[c], kf[hf][c], s[hf], 0, 0, 0);
    }

    float p0[4], p1[4];
#pragma unroll
    for (int i = 0; i < 4; ++i) {
      const int row = q0w + quad * 4 + i;
      const int col0 = kt * 32 + l16, col1 = col0 + 16;
      const float e0 = __expf(s[0][i] * scale);
      const float e1 = __expf(s[1][i] * scale);
      p0[i] = (col0 <= row) ? e0 : 0.f;
      p1[i] = (col1 <= row) ? e1 : 0.f;
      lp[i] += p0[i] + p1[i];
    }
    _Float16* pw = lP[wave];
#pragma unroll
    for (int i = 0; i < 4; ++i) {
      pw[(quad * 4 + i) * 40 + l16] = (_Float16)p0[i];
      pw[(quad * 4 + i) * 40 + l16 + 16] = (_Float16)p1[i];
    }
    half8v pa = *(half8v*)&pw[l16 * 40 + quad * 8];

#pragma unroll
    for (int c = 0; c < 8; ++c)
      o[c] = __builtin_amdgcn_mfma_f32_16x16x32_f16(pa, vf[c], o[c], 0, 0, 0);
  }

  f32x4 ls = lp;
#pragma unroll
  for (int off = 1; off < 16; off <<= 1) {
#pragma unroll
    for (int i = 0; i < 4; ++i) ls[i] += __shfl_xor(ls[i], off);
  }
  f32x4 inv;
#pragma unroll
  for (int i = 0; i < 4; ++i) inv[i] = 1.f / ls[i];
#pragma unroll
  for (int c = 0; c < 8; ++c) {
#pragma unroll
    for (int i = 0; i < 4; ++i) {
      const int row = q0w + quad * 4 + i;
      O[(size_t)row * HID_DIM + h * HD + c * 16 + l16] = (_Float16)(o[c][i] * inv[i]);
    }
  }
}

extern "C" void kernel_launch(void* const* d_in, const int* in_sizes, int n_in,
                              void* d_out, int out_size, void* d_ws, size_t ws_size,
                              hipStream_t stream) {
  const float* hidden = (const float*)d_in[0];
  const int* pos = (const int*)d_in[1];
  const int* qkv_w = (const int*)d_in[2];
  const float* qkv_s = (const float*)d_in[3];
  const float* qkv_z = (const float*)d_in[4];
  const int* o_w = (const int*)d_in[5];
  const float* o_s = (const float*)d_in[6];
  const float* o_z = (const float*)d_in[7];

  // workspace overlays (160 MiB total)
  char* ws = (char*)d_ws;
  _Float16* Wt_qkv = (_Float16*)(ws + 0);
  _Float16* Qb = (_Float16*)(ws + 0);
  _Float16* Kb = (_Float16*)(ws + 16777216);
  _Float16* Vtb = (_Float16*)(ws + 33554432);
  _Float16* Af16 = (_Float16*)(ws + 100663296);
  _Float16* attn = (_Float16*)(ws + 100663296);
  _Float16* proj = (_Float16*)(ws + 117440512);
  _Float16* Wt_o = (_Float16*)(ws + 117440512);
  float* out = (float*)d_out;

  hipLaunchKernelGGL(dequant_w, dim3(192, 64), dim3(256), 0, stream,
                     qkv_w, qkv_s, qkv_z, Wt_qkv, 4096, 12288);
  hipLaunchKernelGGL(conv_a, dim3(8192), dim3(256), 0, stream, hidden, Af16);
  hipLaunchKernelGGL((gemm_f16<_Float16>), dim3(96, 16), dim3(256), 0, stream,
                     Af16, Wt_qkv, proj, 2048, 12288, 4096);
  hipLaunchKernelGGL(rope_kernel, dim3(32, 32), dim3(256), 0, stream, proj, pos, Qb, Kb, Vtb);
  hipLaunchKernelGGL(dequant_w, dim3(64, 64), dim3(256), 0, stream,
                     o_w, o_s, o_z, Wt_o, 4096, 4096);
  hipLaunchKernelGGL(flash_attn, dim3(32, 32), dim3(256), 0, stream, Qb, Kb, Vtb, attn);
  hipLaunchKernelGGL((gemm_f16<float>), dim3(32, 16), dim3(256), 0, stream,
                     attn, Wt_o, out, 2048, 4096, 4096);
}

// Round 8
// 839.253 us; speedup vs baseline: 1.5180x; 1.5180x over previous
//
#include <hip/hip_runtime.h>
#include <hip/hip_bf16.h>

#define S_LEN 2048
#define HID_DIM 4096
#define NH 32
#define HD 128
#define NQKV 12288

typedef _Float16 half2v __attribute__((ext_vector_type(2)));
typedef _Float16 half4v __attribute__((ext_vector_type(4)));
typedef _Float16 half8v __attribute__((ext_vector_type(8)));
typedef float f32x4 __attribute__((ext_vector_type(4)));

typedef const __attribute__((address_space(1))) unsigned int* gas_u32;
typedef __attribute__((address_space(3))) unsigned int* las_u32;

__device__ inline void g2lds16(const _Float16* g, _Float16* l) {
  __builtin_amdgcn_global_load_lds((gas_u32)g, (las_u32)l, 16, 0, 0);
}

__device__ inline void store_out(_Float16* p, float v) { *p = (_Float16)v; }
__device__ inline void store_out(float* p, float v) { *p = v; }

// ---------------- dequant W[K,N] int32 -> Wt[N,K] f16 (transposed) ----------------
__global__ __launch_bounds__(256) void dequant_w(const int* __restrict__ W,
                                                 const float* __restrict__ scal,
                                                 const float* __restrict__ zer,
                                                 _Float16* __restrict__ Wt, int K, int N) {
  __shared__ _Float16 lT[64 * 84];  // [n][k]
  const int k0 = blockIdx.y * 64, n0 = blockIdx.x * 64;
  const int tid = threadIdx.x, c = tid & 63, rp = tid >> 6;
  const int g = k0 >> 7;  // 64 | 128 -> group uniform over tile
  const float sc = scal[(size_t)g * N + n0 + c];
  const float zp = zer[(size_t)g * N + n0 + c];
#pragma unroll
  for (int i = 0; i < 8; ++i) {
    const int k = i * 8 + rp * 2;
    const float q0 = (float)W[(size_t)(k0 + k) * N + n0 + c];
    const float q1 = (float)W[(size_t)(k0 + k + 1) * N + n0 + c];
    half2v p;
    p[0] = (_Float16)((q0 - zp) * sc);
    p[1] = (_Float16)((q1 - zp) * sc);
    *(half2v*)&lT[c * 84 + k] = p;
  }
  __syncthreads();
  const int kc = tid & 7, nr0 = tid >> 3;
#pragma unroll
  for (int i = 0; i < 2; ++i) {
    const int n = nr0 + 32 * i;
    union { half8v v8; half4v v4[2]; } u;
    u.v4[0] = *(const half4v*)&lT[n * 84 + kc * 8];
    u.v4[1] = *(const half4v*)&lT[n * 84 + kc * 8 + 4];
    *(half8v*)&Wt[(size_t)(n0 + n) * K + k0 + kc * 8] = u.v8;
  }
}

// ---------------- hidden f32 -> f16 ----------------
__global__ __launch_bounds__(256) void conv_a(const float* __restrict__ A, _Float16* __restrict__ Af) {
  const int i = blockIdx.x * 256 + threadIdx.x;
  const float4 t = ((const float4*)A)[i];
  half4v r;
  r[0] = (_Float16)t.x; r[1] = (_Float16)t.y; r[2] = (_Float16)t.z; r[3] = (_Float16)t.w;
  ((half4v*)Af)[i] = r;
}

// ---------------- m97-structure f16 GEMM + XOR-swizzled LDS ----------------
template <typename CT>
__global__ __launch_bounds__(256) void gemm_f16(const _Float16* __restrict__ A,
                                                const _Float16* __restrict__ Bt,
                                                CT* __restrict__ C, int M, int N, int K) {
  __shared__ _Float16 lA[128 * 32];
  __shared__ _Float16 lB[128 * 32];

  const int tid = threadIdx.x;
  const int wave = tid >> 6, lane = tid & 63;
  const int quad = lane >> 4, l16 = lane & 15;
  const int wr = wave >> 1, wc = wave & 1;
  const int mb = blockIdx.y, nb = blockIdx.x;

  f32x4 acc[4][4];
  const f32x4 zero4 = {0.f, 0.f, 0.f, 0.f};
#pragma unroll
  for (int mt = 0; mt < 4; ++mt)
#pragma unroll
    for (int nt = 0; nt < 4; ++nt) acc[mt][nt] = zero4;

  const _Float16* Ab = A + (size_t)(mb * 128) * K;
  const _Float16* Bb = Bt + (size_t)(nb * 128) * K;
  const int lrow = lane >> 2;
  const int lkc = ((lane & 3) ^ ((lane >> 3) & 3)) * 8;
  const int sq = (quad ^ ((l16 >> 1) & 3)) * 8;

  for (int k0 = 0; k0 < K; k0 += 32) {
#pragma unroll
    for (int p = 0; p < 2; ++p) {
      const int issue = wave * 2 + p;
      const int row = issue * 16 + lrow;
      g2lds16(Ab + (size_t)row * K + k0 + lkc, &lA[issue * 512]);
      g2lds16(Bb + (size_t)row * K + k0 + lkc, &lB[issue * 512]);
    }
    __syncthreads();

    half8v af[4], bf[4];
#pragma unroll
    for (int mt = 0; mt < 4; ++mt) af[mt] = *(half8v*)&lA[(wr * 64 + mt * 16 + l16) * 32 + sq];
#pragma unroll
    for (int nt = 0; nt < 4; ++nt) bf[nt] = *(half8v*)&lB[(wc * 64 + nt * 16 + l16) * 32 + sq];
#pragma unroll
    for (int mt = 0; mt < 4; ++mt)
#pragma unroll
      for (int nt = 0; nt < 4; ++nt)
        acc[mt][nt] = __builtin_amdgcn_mfma_f32_16x16x32_f16(af[mt], bf[nt], acc[mt][nt], 0, 0, 0);
    __syncthreads();
  }

#pragma unroll
  for (int mt = 0; mt < 4; ++mt) {
#pragma unroll
    for (int nt = 0; nt < 4; ++nt) {
#pragma unroll
      for (int i = 0; i < 4; ++i) {
        const int row = mb * 128 + wr * 64 + mt * 16 + quad * 4 + i;
        const int col = nb * 128 + wc * 64 + nt * 16 + l16;
        store_out(C + (size_t)row * N + col, acc[mt][nt][i]);
      }
    }
  }
}

// ---------------- RoPE on Q,K -> [h][s][d]; V -> Vt [h][d][s] ----------------
__global__ __launch_bounds__(256) void rope_kernel(const _Float16* __restrict__ proj,
                                                   const int* __restrict__ pos,
                                                   _Float16* __restrict__ Q, _Float16* __restrict__ K,
                                                   _Float16* __restrict__ Vt) {
  const int h = blockIdx.x, sb = blockIdx.y;
  const int tid = threadIdx.x;
  const int s0 = sb * 64;

#pragma unroll
  for (int it = 0; it < 16; ++it) {
    const int idx = it * 256 + tid;
    const int sl = idx >> 6, j = idx & 63;
    const int s = s0 + sl;
    const float p = (float)pos[s];
    const float invrev = exp2f(-0.20762050593045455f * (float)j) * 0.15915494309189535f;
    const float rev = p * invrev;
    const float frac = rev - floorf(rev);
    const float sn = __builtin_amdgcn_sinf(frac);
    const float cs = __builtin_amdgcn_cosf(frac);
    const _Float16* rp = proj + (size_t)s * NQKV + h * HD;
    {
      const float x1 = (float)rp[j], x2 = (float)rp[j + 64];
      _Float16* qp = Q + ((size_t)h * S_LEN + s) * HD;
      qp[j] = (_Float16)(x1 * cs - x2 * sn);
      qp[j + 64] = (_Float16)(x2 * cs + x1 * sn);
    }
    {
      const float x1 = (float)rp[HID_DIM + j], x2 = (float)rp[HID_DIM + j + 64];
      _Float16* kp = K + ((size_t)h * S_LEN + s) * HD;
      kp[j] = (_Float16)(x1 * cs - x2 * sn);
      kp[j + 64] = (_Float16)(x2 * cs + x1 * sn);
    }
  }

  __shared__ _Float16 lV[64 * 132];
#pragma unroll
  for (int r = 0; r < 4; ++r) {
    const int cid = r * 256 + tid;
    const int sl = cid >> 4;
    const int d0 = (cid & 15) * 8;
    const _Float16* vp = proj + (size_t)(s0 + sl) * NQKV + 2 * HID_DIM + h * HD + d0;
    *(half4v*)&lV[sl * 132 + d0] = *(const half4v*)vp;
    *(half4v*)&lV[sl * 132 + d0 + 4] = *(const half4v*)(vp + 4);
  }
  __syncthreads();
#pragma unroll
  for (int it = 0; it < 32; ++it) {
    const int d = it * 4 + (tid >> 6);
    const int sl = tid & 63;
    Vt[((size_t)h * HD + d) * S_LEN + s0 + sl] = lV[sl * 132 + d];
  }
}

// ---------------- flash attention: gemm-style LDS K/V staging shared by 4 waves ----------------
// q-block = 128 rows (wave = 32 rows, 2 rowsets). Per 32-col tile: 16 global_load_lds
// (vs 64 per-wave loads before). XOR-swizzled LDS slots -> 2-way (free) frag reads.
__global__ __launch_bounds__(256) void flash_attn(const _Float16* __restrict__ Q,
                                                  const _Float16* __restrict__ Km,
                                                  const _Float16* __restrict__ Vt,
                                                  _Float16* __restrict__ O) {
  __shared__ _Float16 lK[32 * 128];       // [s][d], 16B slot s' = chunk ^ (row&15)
  __shared__ _Float16 lV[128 * 32];       // [d][s], 16B slot s' = chunk ^ ((row>>1)&3)
  __shared__ _Float16 lP[4][2][16 * 40];  // per-wave P staging
  const int h = blockIdx.y;
  const int xb = blockIdx.x;
  const int qb = (xb & 1) ? (15 - (xb >> 1)) : (xb >> 1);  // light/heavy pairing
  const int tid = threadIdx.x;
  const int wave = tid >> 6, lane = tid & 63;
  const int quad = lane >> 4, l16 = lane & 15;
  const int q0w = qb * 128 + wave * 32;
  const float scale = 0.08838834764831845f;

  const _Float16* Qh = Q + (size_t)h * S_LEN * HD;
  const _Float16* Kh = Km + (size_t)h * S_LEN * HD;
  const _Float16* Vh = Vt + (size_t)h * HD * S_LEN;

  // staging lane roles
  const int kRow0 = wave * 8 + (lane >> 4);   // K: rows wave*8..+7 over 2 issues
  const int kSlot = lane & 15;
  const int vRow0 = wave * 32 + (lane >> 2);  // V: rows wave*32..+31 over 2 issues
  const int vSlot = lane & 3;

  half8v qf[2][4];
#pragma unroll
  for (int r = 0; r < 2; ++r)
#pragma unroll
    for (int c = 0; c < 4; ++c)
      qf[r][c] = *(const half8v*)&Qh[(size_t)(q0w + r * 16 + l16) * HD + c * 32 + quad * 8];

  const f32x4 zero4 = {0.f, 0.f, 0.f, 0.f};
  f32x4 o[2][8];
  f32x4 lp[2];
#pragma unroll
  for (int r = 0; r < 2; ++r) {
    lp[r] = zero4;
#pragma unroll
    for (int c = 0; c < 8; ++c) o[r][c] = zero4;
  }

  const int ntiles = 4 * qb + 4;  // uniform per block (barriers legal)
  for (int kt = 0; kt < ntiles; ++kt) {
    // ---- cooperative staging: K tile (32x128) + V tile (128x32), swizzled ----
#pragma unroll
    for (int i = 0; i < 2; ++i) {
      const int row = kRow0 + i * 4;
      const int ck = kSlot ^ (row & 15);
      g2lds16(Kh + (size_t)(kt * 32 + row) * HD + ck * 8, &lK[(wave * 8 + i * 4) * 128]);
    }
#pragma unroll
    for (int i = 0; i < 2; ++i) {
      const int row = vRow0 + i * 16;
      const int cv = vSlot ^ ((row >> 1) & 3);
      g2lds16(Vh + (size_t)row * S_LEN + kt * 32 + cv * 8, &lV[(wave * 32 + i * 16) * 32]);
    }
    __syncthreads();

    // ---- fragments from LDS (swizzled reads, 2-way = free) ----
    half8v kf[2][4];
#pragma unroll
    for (int hf = 0; hf < 2; ++hf)
#pragma unroll
      for (int c = 0; c < 4; ++c) {
        const int slot = (c * 4 + quad) ^ l16;
        kf[hf][c] = *(const half8v*)&lK[(hf * 16 + l16) * 128 + slot * 8];
      }
    half8v vf[8];
#pragma unroll
    for (int c = 0; c < 8; ++c) {
      const int slot = quad ^ ((l16 >> 1) & 3);
      vf[c] = *(const half8v*)&lV[(c * 16 + l16) * 32 + slot * 8];
    }

    // ---- QK^T ----
    f32x4 s[2][2];
#pragma unroll
    for (int r = 0; r < 2; ++r)
#pragma unroll
      for (int hf = 0; hf < 2; ++hf) {
        s[r][hf] = zero4;
#pragma unroll
        for (int c = 0; c < 4; ++c)
          s[r][hf] = __builtin_amdgcn_mfma_f32_16x16x32_f16(qf[r][c], kf[hf][c], s[r][hf], 0, 0, 0);
      }

    // ---- exp + mask + P staging (per-wave LDS, intra-wave) ----
#pragma unroll
    for (int r = 0; r < 2; ++r) {
      float p0[4], p1[4];
#pragma unroll
      for (int i = 0; i < 4; ++i) {
        const int row = q0w + r * 16 + quad * 4 + i;
        const int col0 = kt * 32 + l16, col1 = col0 + 16;
        const float e0 = __expf(s[r][0][i] * scale);
        const float e1 = __expf(s[r][1][i] * scale);
        p0[i] = (col0 <= row) ? e0 : 0.f;
        p1[i] = (col1 <= row) ? e1 : 0.f;
        lp[r][i] += p0[i] + p1[i];
      }
      _Float16* pw = lP[wave][r];
#pragma unroll
      for (int i = 0; i < 4; ++i) {
        pw[(quad * 4 + i) * 40 + l16] = (_Float16)p0[i];
        pw[(quad * 4 + i) * 40 + l16 + 16] = (_Float16)p1[i];
      }
    }
    half8v pa[2];
#pragma unroll
    for (int r = 0; r < 2; ++r) pa[r] = *(half8v*)&lP[wave][r][l16 * 40 + quad * 8];

    // ---- PV ----
#pragma unroll
    for (int c = 0; c < 8; ++c)
#pragma unroll
      for (int r = 0; r < 2; ++r)
        o[r][c] = __builtin_amdgcn_mfma_f32_16x16x32_f16(pa[r], vf[c], o[r][c], 0, 0, 0);

    __syncthreads();
  }

#pragma unroll
  for (int r = 0; r < 2; ++r) {
    f32x4 ls = lp[r];
#pragma unroll
    for (int off = 1; off < 16; off <<= 1) {
#pragma unroll
      for (int i = 0; i < 4; ++i) ls[i] += __shfl_xor(ls[i], off);
    }
    f32x4 inv;
#pragma unroll
    for (int i = 0; i < 4; ++i) inv[i] = 1.f / ls[i];
#pragma unroll
    for (int c = 0; c < 8; ++c) {
#pragma unroll
      for (int i = 0; i < 4; ++i) {
        const int row = q0w + r * 16 + quad * 4 + i;
        O[(size_t)row * HID_DIM + h * HD + c * 16 + l16] = (_Float16)(o[r][c][i] * inv[i]);
      }
    }
  }
}

extern "C" void kernel_launch(void* const* d_in, const int* in_sizes, int n_in,
                              void* d_out, int out_size, void* d_ws, size_t ws_size,
                              hipStream_t stream) {
  const float* hidden = (const float*)d_in[0];
  const int* pos = (const int*)d_in[1];
  const int* qkv_w = (const int*)d_in[2];
  const float* qkv_s = (const float*)d_in[3];
  const float* qkv_z = (const float*)d_in[4];
  const int* o_w = (const int*)d_in[5];
  const float* o_s = (const float*)d_in[6];
  const float* o_z = (const float*)d_in[7];

  // workspace overlays (160 MiB total)
  char* ws = (char*)d_ws;
  _Float16* Wt_qkv = (_Float16*)(ws + 0);
  _Float16* Qb = (_Float16*)(ws + 0);
  _Float16* Kb = (_Float16*)(ws + 16777216);
  _Float16* Vtb = (_Float16*)(ws + 33554432);
  _Float16* Af16 = (_Float16*)(ws + 100663296);
  _Float16* attn = (_Float16*)(ws + 100663296);
  _Float16* proj = (_Float16*)(ws + 117440512);
  _Float16* Wt_o = (_Float16*)(ws + 117440512);
  float* out = (float*)d_out;

  hipLaunchKernelGGL(dequant_w, dim3(192, 64), dim3(256), 0, stream,
                     qkv_w, qkv_s, qkv_z, Wt_qkv, 4096, 12288);
  hipLaunchKernelGGL(conv_a, dim3(8192), dim3(256), 0, stream, hidden, Af16);
  hipLaunchKernelGGL((gemm_f16<_Float16>), dim3(96, 16), dim3(256), 0, stream,
                     Af16, Wt_qkv, proj, 2048, 12288, 4096);
  hipLaunchKernelGGL(rope_kernel, dim3(32, 32), dim3(256), 0, stream, proj, pos, Qb, Kb, Vtb);
  hipLaunchKernelGGL(dequant_w, dim3(64, 64), dim3(256), 0, stream,
                     o_w, o_s, o_z, Wt_o, 4096, 4096);
  hipLaunchKernelGGL(flash_attn, dim3(16, 32), dim3(256), 0, stream, Qb, Kb, Vtb, attn);
  hipLaunchKernelGGL((gemm_f16<float>), dim3(32, 16), dim3(256), 0, stream,
                     attn, Wt_o, out, 2048, 4096, 4096);
}